// Round 7
// baseline (220.900 us; speedup 1.0000x reference)
//
#include <hip/hip_runtime.h>
#include <hip/hip_bf16.h>

#define N_ROWS 16384
#define D_COLS 2048
#define NUM_LABELS 1024
#define NUM_CAMS 8
#define NUM_SEG (NUM_LABELS * NUM_CAMS)   // 8192
#define MAXPER 64                          // list capacity per segment
#define R_REG 8                            // rows cached in registers (P(cnt>8)~2e-4/seg)
#define INFO_INTS 16                       // seginfo record: cnt + 12 idx + pad -> 64 B
#define INFO_IDX 12                        // indices stored in seginfo
#define F4_PER_ROW (D_COLS / 4)            // 512 float4 per row
#define NUM_BLOCKS (NUM_SEG * 2)           // one block per (segment, column-half)

// ---------------- kernel 1: build per-segment row lists ----------------
__global__ void build_lists_kernel(const int* __restrict__ labels,
                                   const int* __restrict__ cams,
                                   int* __restrict__ counts,
                                   int* __restrict__ lists) {
    int i = blockIdx.x * blockDim.x + threadIdx.x;
    if (i < N_ROWS) {
        int seg = labels[i] * NUM_CAMS + cams[i];
        int pos = atomicAdd(&counts[seg], 1);
        if (pos < MAXPER) lists[seg * MAXPER + pos] = i;
    }
}

// ---------------- kernel 2: repack counts+lists into one 64B record/segment ----
// seg_loss then needs ONE uniform (scalar) 64B load for all its metadata.
__global__ __launch_bounds__(256) void repack_kernel(const int* __restrict__ counts,
                                                     const int* __restrict__ lists,
                                                     int* __restrict__ seginfo) {
    int seg = blockIdx.x * blockDim.x + threadIdx.x;
    if (seg < NUM_SEG) {
        int cnt = counts[seg];
        int c = cnt < INFO_IDX ? cnt : INFO_IDX;
        int* o = seginfo + seg * INFO_INTS;
        o[0] = cnt;
#pragma unroll
        for (int r = 0; r < INFO_IDX; ++r)
            o[1 + r] = (r < c) ? lists[seg * MAXPER + r] : 0;
    }
}

__device__ __forceinline__ float smooth_l1(float d) {
    float ad = fabsf(d);
    return ad < 1.0f ? 0.5f * d * d : ad - 0.5f;
}

// ---------------- kernel 3: one block per (segment, column-half) ----------------
// Metadata via block-uniform seginfo record (scalar loads, chain depth 2:
// info -> row data). R_REG rows cached in registers, all loads in flight
// together. __launch_bounds__(256,8): VGPR<=64 -> 8 blocks/CU -> 8 generations.
// cnt>R_REG handled by a rare streamed slow path (correct, not fast).
__global__ __launch_bounds__(256, 8) void seg_loss_kernel(const float* __restrict__ feats,
                                                          const int* __restrict__ seginfo,
                                                          const int* __restrict__ lists,
                                                          float* __restrict__ partials) {
    int bid  = blockIdx.x;
    int seg  = bid >> 1;
    int half = bid & 1;
    int tid  = threadIdx.x;

    const int* info = seginfo + seg * INFO_INTS;   // uniform -> s_load
    int cnt  = info[0];
    int rows = cnt < R_REG ? cnt : R_REG;          // uniform

    const float4* base = (const float4*)feats + (half * 256 + tid);

    // all cached-row loads issued back-to-back (uniform branches skip excess)
    float4 v[R_REG];
#pragma unroll
    for (int r = 0; r < R_REG; ++r) {
        v[r] = make_float4(0.f, 0.f, 0.f, 0.f);
        if (r < rows)
            v[r] = base[(size_t)info[1 + r] * F4_PER_ROW];
    }

    float mx = 0.f, my = 0.f, mz = 0.f, mw = 0.f;
#pragma unroll
    for (int r = 0; r < R_REG; ++r) {
        mx += v[r].x; my += v[r].y; mz += v[r].z; mw += v[r].w;
    }

    // rare slow path: stream-add rows R_REG..cnt-1 (indices from seginfo then lists)
    if (cnt > R_REG) {
        for (int r = R_REG; r < cnt && r < INFO_IDX; ++r) {
            float4 a = base[(size_t)info[1 + r] * F4_PER_ROW];
            mx += a.x; my += a.y; mz += a.z; mw += a.w;
        }
        for (int r = INFO_IDX; r < cnt && r < MAXPER; ++r) {
            float4 a = base[(size_t)lists[seg * MAXPER + r] * F4_PER_ROW];
            mx += a.x; my += a.y; mz += a.z; mw += a.w;
        }
    }

    float inv = 1.0f / (float)(cnt > 0 ? cnt : 1);
    mx *= inv; my *= inv; mz *= inv; mw *= inv;

    // loss from cached registers (single global pass on the fast path)
    float loss = 0.0f;
#pragma unroll
    for (int r = 0; r < R_REG; ++r) {
        float w = (r < rows) ? 1.0f : 0.0f;
        loss += w * (smooth_l1(v[r].x - mx) + smooth_l1(v[r].y - my)
                   + smooth_l1(v[r].z - mz) + smooth_l1(v[r].w - mw));
    }
    if (cnt > R_REG) {   // rare slow path: re-stream tail rows for loss
        for (int r = R_REG; r < cnt && r < INFO_IDX; ++r) {
            float4 a = base[(size_t)info[1 + r] * F4_PER_ROW];
            loss += smooth_l1(a.x - mx) + smooth_l1(a.y - my)
                  + smooth_l1(a.z - mz) + smooth_l1(a.w - mw);
        }
        for (int r = INFO_IDX; r < cnt && r < MAXPER; ++r) {
            float4 a = base[(size_t)lists[seg * MAXPER + r] * F4_PER_ROW];
            loss += smooth_l1(a.x - mx) + smooth_l1(a.y - my)
                  + smooth_l1(a.z - mz) + smooth_l1(a.w - mw);
        }
    }

    // block reduction: wave64 shuffle then LDS across 4 waves
    for (int o = 32; o > 0; o >>= 1)
        loss += __shfl_down(loss, o, 64);

    __shared__ float wsum[4];
    int lane = tid & 63;
    int wid  = tid >> 6;
    if (lane == 0) wsum[wid] = loss;
    __syncthreads();
    if (tid == 0)
        partials[bid] = wsum[0] + wsum[1] + wsum[2] + wsum[3];
}

// ---------------- kernel 4: reduce partials -> scalar loss ----------------
__global__ __launch_bounds__(256) void reduce_kernel(const float* __restrict__ partials,
                                                     float* __restrict__ out) {
    int tid = threadIdx.x;
    float s = 0.0f;
    for (int i = tid; i < NUM_BLOCKS; i += 256)
        s += partials[i];

    for (int o = 32; o > 0; o >>= 1)
        s += __shfl_down(s, o, 64);

    __shared__ float wsum[4];
    int lane = tid & 63;
    int wid  = tid >> 6;
    if (lane == 0) wsum[wid] = s;
    __syncthreads();
    if (tid == 0)
        out[0] = (wsum[0] + wsum[1] + wsum[2] + wsum[3])
               * (1.0f / ((float)N_ROWS * (float)D_COLS));
}

extern "C" void kernel_launch(void* const* d_in, const int* in_sizes, int n_in,
                              void* d_out, int out_size, void* d_ws, size_t ws_size,
                              hipStream_t stream) {
    const float* feats = (const float*)d_in[0];
    const int* labels  = (const int*)d_in[1];
    const int* cams    = (const int*)d_in[2];
    float* out = (float*)d_out;

    // ws layout: counts[NUM_SEG] | lists[NUM_SEG*MAXPER] | seginfo[NUM_SEG*16] | partials[NUM_BLOCKS]
    int* counts     = (int*)d_ws;
    int* lists      = counts + NUM_SEG;
    int* seginfo    = lists + NUM_SEG * MAXPER;
    float* partials = (float*)(seginfo + NUM_SEG * INFO_INTS);

    hipMemsetAsync(counts, 0, NUM_SEG * sizeof(int), stream);   // only counts need zeroing

    build_lists_kernel<<<(N_ROWS + 255) / 256, 256, 0, stream>>>(labels, cams, counts, lists);
    repack_kernel<<<(NUM_SEG + 255) / 256, 256, 0, stream>>>(counts, lists, seginfo);
    seg_loss_kernel<<<NUM_BLOCKS, 256, 0, stream>>>(feats, seginfo, lists, partials);
    reduce_kernel<<<1, 256, 0, stream>>>(partials, out);
}

// Round 8
// 204.912 us; speedup vs baseline: 1.0780x; 1.0780x over previous
//
#include <hip/hip_runtime.h>
#include <hip/hip_bf16.h>

#define N_ROWS 16384
#define D_COLS 2048
#define NUM_LABELS 1024
#define NUM_CAMS 8
#define NUM_SEG (NUM_LABELS * NUM_CAMS)   // 8192
#define MAXPER 64                          // list capacity per segment
#define GSEG 8                             // segments per block
#define NUM_GROUPS (NUM_SEG / GSEG)        // 1024
#define NUM_BLOCKS (NUM_GROUPS * 2)        // 2048 blocks: (group, column-half) -> 8/CU, ALL resident
#define FAST_R 8                           // register-cached rows per segment (P(cnt>8) ~ 3e-4/seg)
#define IDX_LDS 12                         // indices staged in LDS per segment
#define F4_PER_ROW (D_COLS / 4)            // 512 float4 per row

// ---------------- kernel 1: build per-segment row lists ----------------
__global__ void build_lists_kernel(const int* __restrict__ labels,
                                   const int* __restrict__ cams,
                                   int* __restrict__ counts,
                                   int* __restrict__ lists) {
    int i = blockIdx.x * blockDim.x + threadIdx.x;
    if (i < N_ROWS) {
        int seg = labels[i] * NUM_CAMS + cams[i];
        int pos = atomicAdd(&counts[seg], 1);
        if (pos < MAXPER) lists[seg * MAXPER + pos] = i;
    }
}

__device__ __forceinline__ float smooth_l1(float d) {
    float ad = fabsf(d);
    return ad < 1.0f ? 0.5f * d * d : ad - 0.5f;
}

// ---------------- kernel 2: one block per (8 segments, column-half) ----------------
// 2048 blocks = 8/CU, all co-resident: NO sequential block generations.
// Phase 0: stage counts + first 12 row indices per segment into LDS (one
// coalesced load, one barrier). Then loop segments: <=FAST_R predicated
// parallel loads cached in registers (single global pass, 134 MB total),
// mean, SmoothL1 from registers. Segment loop kept ROLLED so VGPR stays
// under 64 at __launch_bounds__(256,8); overlap comes from 8 resident blocks.
__global__ __launch_bounds__(256, 8) void group_loss_kernel(const float* __restrict__ feats,
                                                            const int* __restrict__ counts,
                                                            const int* __restrict__ lists,
                                                            float* __restrict__ partials) {
    int bid  = blockIdx.x;
    int grp  = bid >> 1;
    int half = bid & 1;
    int tid  = threadIdx.x;
    int seg0 = grp * GSEG;

    __shared__ int   scnt[GSEG];
    __shared__ int   sidx[GSEG][IDX_LDS];
    __shared__ float wsum[4];

    // phase 0: metadata -> LDS (threads 0..7 counts, 8..103 indices)
    if (tid < GSEG) {
        scnt[tid] = counts[seg0 + tid];
    } else if (tid < GSEG + GSEG * IDX_LDS) {
        int j = tid - GSEG;
        int s = j / IDX_LDS;
        int r = j - s * IDX_LDS;
        // may read unwritten (poison) list slots; masked by cnt before any use
        sidx[s][r] = lists[(seg0 + s) * MAXPER + r];
    }
    __syncthreads();

    const float4* base = (const float4*)feats + (half * 256 + tid);
    float loss = 0.0f;

#pragma unroll 1   // keep rolled: VGPR budget; cross-block residency provides overlap
    for (int s = 0; s < GSEG; ++s) {
        int cnt  = scnt[s];                        // block-uniform
        int rows = cnt < FAST_R ? cnt : FAST_R;

        // predicated parallel loads, cached in registers (zeros where unused)
        float4 v[FAST_R];
#pragma unroll
        for (int r = 0; r < FAST_R; ++r) {
            v[r] = make_float4(0.f, 0.f, 0.f, 0.f);
            if (r < rows)
                v[r] = base[(size_t)sidx[s][r] * F4_PER_ROW];
        }

        float mx = 0.f, my = 0.f, mz = 0.f, mw = 0.f;
#pragma unroll
        for (int r = 0; r < FAST_R; ++r) {
            mx += v[r].x; my += v[r].y; mz += v[r].z; mw += v[r].w;
        }

        if (cnt > FAST_R) {   // rare tail (cnt>8): stream-add
            for (int r = FAST_R; r < cnt && r < IDX_LDS; ++r) {
                float4 a = base[(size_t)sidx[s][r] * F4_PER_ROW];
                mx += a.x; my += a.y; mz += a.z; mw += a.w;
            }
            for (int r = IDX_LDS; r < cnt && r < MAXPER; ++r) {
                float4 a = base[(size_t)lists[(seg0 + s) * MAXPER + r] * F4_PER_ROW];
                mx += a.x; my += a.y; mz += a.z; mw += a.w;
            }
        }

        float inv = 1.0f / (float)(cnt > 0 ? cnt : 1);
        mx *= inv; my *= inv; mz *= inv; mw *= inv;

        // loss from cached registers (no reload on the fast path)
#pragma unroll
        for (int r = 0; r < FAST_R; ++r) {
            if (r < rows)
                loss += smooth_l1(v[r].x - mx) + smooth_l1(v[r].y - my)
                      + smooth_l1(v[r].z - mz) + smooth_l1(v[r].w - mw);
        }
        if (cnt > FAST_R) {   // rare tail: re-stream (L2-hot)
            for (int r = FAST_R; r < cnt && r < IDX_LDS; ++r) {
                float4 a = base[(size_t)sidx[s][r] * F4_PER_ROW];
                loss += smooth_l1(a.x - mx) + smooth_l1(a.y - my)
                      + smooth_l1(a.z - mz) + smooth_l1(a.w - mw);
            }
            for (int r = IDX_LDS; r < cnt && r < MAXPER; ++r) {
                float4 a = base[(size_t)lists[(seg0 + s) * MAXPER + r] * F4_PER_ROW];
                loss += smooth_l1(a.x - mx) + smooth_l1(a.y - my)
                      + smooth_l1(a.z - mz) + smooth_l1(a.w - mw);
            }
        }
    }

    // block reduction: wave64 shuffle then LDS across 4 waves
    for (int o = 32; o > 0; o >>= 1)
        loss += __shfl_down(loss, o, 64);

    int lane = tid & 63;
    int wid  = tid >> 6;
    if (lane == 0) wsum[wid] = loss;
    __syncthreads();
    if (tid == 0)
        partials[bid] = wsum[0] + wsum[1] + wsum[2] + wsum[3];
}

// ---------------- kernel 3: reduce partials -> scalar loss ----------------
__global__ __launch_bounds__(256) void reduce_kernel(const float* __restrict__ partials,
                                                     float* __restrict__ out) {
    int tid = threadIdx.x;
    float s = 0.0f;
    for (int i = tid; i < NUM_BLOCKS; i += 256)
        s += partials[i];

    for (int o = 32; o > 0; o >>= 1)
        s += __shfl_down(s, o, 64);

    __shared__ float wsum[4];
    int lane = tid & 63;
    int wid  = tid >> 6;
    if (lane == 0) wsum[wid] = s;
    __syncthreads();
    if (tid == 0)
        out[0] = (wsum[0] + wsum[1] + wsum[2] + wsum[3])
               * (1.0f / ((float)N_ROWS * (float)D_COLS));
}

extern "C" void kernel_launch(void* const* d_in, const int* in_sizes, int n_in,
                              void* d_out, int out_size, void* d_ws, size_t ws_size,
                              hipStream_t stream) {
    const float* feats = (const float*)d_in[0];
    const int* labels  = (const int*)d_in[1];
    const int* cams    = (const int*)d_in[2];
    float* out = (float*)d_out;

    // ws layout: counts[NUM_SEG] | lists[NUM_SEG*MAXPER] | partials[NUM_BLOCKS]
    int* counts     = (int*)d_ws;
    int* lists      = counts + NUM_SEG;
    float* partials = (float*)(lists + NUM_SEG * MAXPER);

    hipMemsetAsync(counts, 0, NUM_SEG * sizeof(int), stream);   // only counts need zeroing

    build_lists_kernel<<<(N_ROWS + 255) / 256, 256, 0, stream>>>(labels, cams, counts, lists);
    group_loss_kernel<<<NUM_BLOCKS, 256, 0, stream>>>(feats, counts, lists, partials);
    reduce_kernel<<<1, 256, 0, stream>>>(partials, out);
}